// Round 6
// baseline (302.584 us; speedup 1.0000x reference)
//
#include <hip/hip_runtime.h>
#include <math.h>
#include <stddef.h>

#define HQ   16
#define HKV  8
#define DH   128
#define HID  2048
#define CC   16384
#define NCH  32             // position chunks of 512 in k_softpv
#define CHUNK 512
#define NDG  4              // dim-groups of 32 in k_scores

// d_out layout (FLOAT32, 4096 elements): [attn 2048][k_new 8*128][v 8*128]
//
// ws layout (floats):
//   raw     @0        (4096)
//   qf      @4096     (2048)
//   kf      @6144     (1024)      (vnew = raw+3072)
//   ps      @8192     (1048576)   partial scores [HKV][NDG][2][CC]
//   opart   @1056768  (65536)     [HQ][NCH][DH]
//   ML      @1122304  (1024)      [HQ][NCH] float2
//   attn_in @1123328  (2048)
//   spin    @1125376  (64)

// ---- K1: QKV projections. One wave per output element.
__global__ void k_qkv(const float* __restrict__ x,
                      const float* __restrict__ Wq,
                      const float* __restrict__ Wk,
                      const float* __restrict__ Wv,
                      float* __restrict__ raw,
                      float* __restrict__ out){
  int wave = threadIdx.x >> 6, lane = threadIdx.x & 63;
  int e = blockIdx.x * 4 + wave;
  const float* W;
  if (e < 2048)      W = Wq + (size_t)e * HID;
  else if (e < 3072) W = Wk + (size_t)(e - 2048) * HID;
  else               W = Wv + (size_t)(e - 3072) * HID;
  float4 wb[8], xb[8];
  #pragma unroll
  for (int j = 0; j < 8; ++j) wb[j] = *(const float4*)(W + (j * 64 + lane) * 4);
  #pragma unroll
  for (int j = 0; j < 8; ++j) xb[j] = *(const float4*)(x + (j * 64 + lane) * 4);
  __builtin_amdgcn_sched_barrier(0);
  float acc = 0.f;
  #pragma unroll
  for (int j = 0; j < 8; ++j)
    acc += wb[j].x*xb[j].x + wb[j].y*xb[j].y + wb[j].z*xb[j].z + wb[j].w*xb[j].w;
  #pragma unroll
  for (int off = 32; off; off >>= 1) acc += __shfl_down(acc, off, 64);
  if (lane == 0){
    raw[e] = acc;
    if (e >= 3072) out[e] = acc;   // v passthrough
  }
}

// ---- K2: RMSNorm + RoPE (q,k). grid=24, 128 threads.
__global__ void k_normrope(const float* __restrict__ raw,
                           const float* __restrict__ cosb,
                           const float* __restrict__ sinb,
                           const float* __restrict__ qw,
                           const float* __restrict__ kw,
                           float* __restrict__ qf,
                           float* __restrict__ kf,
                           float* __restrict__ out){
  __shared__ float lds[DH];
  __shared__ float wsum[2];
  int b = blockIdx.x, t = threadIdx.x;
  bool isq = (b < 16);
  int h = isq ? b : b - 16;
  float val = isq ? raw[h * DH + t] : raw[2048 + h * DH + t];
  float ss = val * val;
  #pragma unroll
  for (int off = 32; off; off >>= 1) ss += __shfl_down(ss, off, 64);
  if ((t & 63) == 0) wsum[t >> 6] = ss;
  __syncthreads();
  float rms = sqrtf((wsum[0] + wsum[1]) / 128.f + 1e-6f);
  float w = isq ? qw[t] : kw[t];
  float normed = val / rms * w;
  lds[t] = normed;
  __syncthreads();
  float rot = (t < 64) ? -lds[t + 64] : lds[t - 64];
  float res = normed * cosb[t] + rot * sinb[t];
  if (isq) qf[h * DH + t] = res;
  else { kf[h * DH + t] = res; out[2048 + h * DH + t] = res; }
}

// ---- K3a: QK^T partial scores, pure streaming (no barriers in hot loop).
// grid = HKV*NDG*8 = 256 blocks x 512 threads.
// Block (kv, dg, cs): dims dg*32..+31, positions cs*2048..+2047.
// Per dim the block touches an 8 KB contiguous run (1 KB per wave-load).
__global__ __launch_bounds__(512) void k_scores(
    const float* __restrict__ qf,
    const float* __restrict__ kcache,  // [HKV][DH][CC]
    float* __restrict__ ps){           // [HKV][NDG][2][CC]
  __shared__ float q_s[2][32];
  int kv = blockIdx.x >> 5, dg = (blockIdx.x >> 3) & 3, cs = blockIdx.x & 7;
  int t = threadIdx.x;
  if (t < 64) q_s[t >> 5][t & 31] = qf[(kv * 2 + (t >> 5)) * DH + dg * 32 + (t & 31)];
  __syncthreads();
  const float* kp = kcache + (size_t)kv * DH * CC + (size_t)(dg * 32) * CC
                  + cs * 2048 + t * 4;
  float a00 = 0.f, a01 = 0.f, a02 = 0.f, a03 = 0.f;
  float a10 = 0.f, a11 = 0.f, a12 = 0.f, a13 = 0.f;
  #pragma unroll
  for (int ib = 0; ib < 4; ++ib){
    float4 kb[8];
    #pragma unroll
    for (int j = 0; j < 8; ++j)
      kb[j] = *(const float4*)(kp + (size_t)(ib * 8 + j) * CC);
    __builtin_amdgcn_sched_barrier(0);
    #pragma unroll
    for (int j = 0; j < 8; ++j){
      float q0 = q_s[0][ib * 8 + j], q1 = q_s[1][ib * 8 + j];
      a00 += q0 * kb[j].x; a01 += q0 * kb[j].y; a02 += q0 * kb[j].z; a03 += q0 * kb[j].w;
      a10 += q1 * kb[j].x; a11 += q1 * kb[j].y; a12 += q1 * kb[j].z; a13 += q1 * kb[j].w;
    }
  }
  size_t base = ((size_t)(kv * NDG + dg) * 2) * CC + cs * 2048 + t * 4;
  *(float4*)(ps + base)      = make_float4(a00, a01, a02, a03);
  *(float4*)(ps + base + CC) = make_float4(a10, a11, a12, a13);
}

// ---- K3b: combine partials, softmax per chunk, PV. grid = HKV*NCH = 256 x 512.
__global__ __launch_bounds__(512) void k_softpv(
    const float* __restrict__ ps,      // [HKV][NDG][2][CC]
    const float* __restrict__ vcache,  // [HKV][CC][DH]
    const float* __restrict__ mask,    // [CC+1]
    float* __restrict__ opart,         // [HQ][NCH][DH]
    float2* __restrict__ ml){          // [HQ][NCH]
  __shared__ float p_s[2][CHUNK];      // 4 KB
  __shared__ float part[2][16][DH];    // 16 KB
  __shared__ float red[32];
  int kv = blockIdx.x >> 5, ch = blockIdx.x & 31;
  int c0 = ch << 9;
  int t = threadIdx.x;
  const float scale = 0.08838834764831845f;  // 128^-0.5

  // gather partial dots for position c0+t, both heads
  float s0 = 0.f, s1 = 0.f;
  #pragma unroll
  for (int dg = 0; dg < NDG; ++dg){
    size_t base = ((size_t)(kv * NDG + dg) * 2) * CC + c0 + t;
    s0 += ps[base];
    s1 += ps[base + CC];
  }
  {
    float mk = mask[c0 + t];
    s0 = s0 * scale + mk;
    s1 = s1 * scale + mk;
  }
  // chunk softmax over 512 positions (8 waves)
  int wv = t >> 6;
  float lm0 = s0, lm1 = s1;
  #pragma unroll
  for (int off = 32; off; off >>= 1){
    lm0 = fmaxf(lm0, __shfl_down(lm0, off, 64));
    lm1 = fmaxf(lm1, __shfl_down(lm1, off, 64));
  }
  if ((t & 63) == 0){ red[wv] = lm0; red[8 + wv] = lm1; }
  __syncthreads();
  float m0 = red[0], m1 = red[8];
  #pragma unroll
  for (int i = 1; i < 8; ++i){
    m0 = fmaxf(m0, red[i]);
    m1 = fmaxf(m1, red[8 + i]);
  }
  float p0 = __expf(s0 - m0);
  float p1 = __expf(s1 - m1);
  p_s[0][t] = p0;
  p_s[1][t] = p1;
  float ls0 = p0, ls1 = p1;
  #pragma unroll
  for (int off = 32; off; off >>= 1){
    ls0 += __shfl_down(ls0, off, 64);
    ls1 += __shfl_down(ls1, off, 64);
  }
  if ((t & 63) == 0){ red[16 + wv] = ls0; red[24 + wv] = ls1; }
  __syncthreads();
  if (t == 0){
    float l0 = 0.f, l1 = 0.f;
    #pragma unroll
    for (int i = 0; i < 8; ++i){ l0 += red[16 + i]; l1 += red[24 + i]; }
    ml[(size_t)(kv * 2)     * NCH + ch] = make_float2(m0, l0);
    ml[(size_t)(kv * 2 + 1) * NCH + ch] = make_float2(m1, l1);
  }

  // PV: 16 pos-slices x 32 dim-lanes; 8-deep pinned batches; V contiguous.
  {
    int sl = t >> 5, d4 = (t & 31) * 4;
    const float* vbase = vcache + (size_t)kv * CC * DH + (size_t)c0 * DH + d4;
    float4 a0 = make_float4(0.f, 0.f, 0.f, 0.f);
    float4 a1 = make_float4(0.f, 0.f, 0.f, 0.f);
    #pragma unroll
    for (int ib = 0; ib < 4; ++ib){
      float4 vv[8];
      #pragma unroll
      for (int j = 0; j < 8; ++j){
        int off = (ib * 8 + j) * 16 + sl;
        vv[j] = *(const float4*)(vbase + (size_t)off * DH);
      }
      __builtin_amdgcn_sched_barrier(0);
      #pragma unroll
      for (int j = 0; j < 8; ++j){
        int off = (ib * 8 + j) * 16 + sl;
        float pp0 = p_s[0][off], pp1 = p_s[1][off];
        a0.x += pp0 * vv[j].x; a0.y += pp0 * vv[j].y; a0.z += pp0 * vv[j].z; a0.w += pp0 * vv[j].w;
        a1.x += pp1 * vv[j].x; a1.y += pp1 * vv[j].y; a1.z += pp1 * vv[j].z; a1.w += pp1 * vv[j].w;
      }
    }
    *(float4*)&part[0][sl][d4] = a0;
    *(float4*)&part[1][sl][d4] = a1;
  }
  __syncthreads();
  if (t < 256){
    int hh = t >> 7, d = t & 127;
    float o = 0.f;
    #pragma unroll
    for (int ss = 0; ss < 16; ++ss) o += part[hh][ss][d];
    int qh = kv * 2 + hh;
    opart[((size_t)qh * NCH + ch) * DH + d] = o;
  }
}

// ---- K4: combine chunk partials + new-token term. grid=HQ, 512 threads.
__global__ void k_combine(const float* __restrict__ opart,
                          const float2* __restrict__ ml,
                          const float* __restrict__ qf,
                          const float* __restrict__ kf,
                          const float* __restrict__ vnew,   // raw+3072: [HKV][DH]
                          const float* __restrict__ mask,
                          float* __restrict__ attn_in){
  __shared__ float osum[4][DH];
  __shared__ float Ls[4];
  __shared__ float redm[8];
  __shared__ float redq[2];
  int qh = blockIdx.x, t = threadIdx.x;
  int g = t >> 7, d = t & 127;
  int kv = qh >> 1;
  const float2* mlrow = ml + (size_t)qh * NCH;
  float mm = mlrow[t & 31].x;
  #pragma unroll
  for (int off = 32; off; off >>= 1) mm = fmaxf(mm, __shfl_down(mm, off, 64));
  if ((t & 63) == 0) redm[t >> 6] = mm;
  __syncthreads();
  float M = fmaxf(redm[0], redm[1]);
  float o = 0.f, L = 0.f;
  int ch0 = g * 8;
  #pragma unroll
  for (int i = 0; i < 8; ++i){
    float2 m2 = mlrow[ch0 + i];
    float w = __expf(m2.x - M);
    L += m2.y * w;
    o += w * opart[((size_t)qh * NCH + ch0 + i) * DH + d];
  }
  osum[g][d] = o;
  if (d == 0) Ls[g] = L;
  if (t < DH){
    float sum = qf[qh * DH + t] * kf[kv * DH + t];
    #pragma unroll
    for (int off = 32; off; off >>= 1) sum += __shfl_down(sum, off, 64);
    if ((t & 63) == 0) redq[t >> 6] = sum;
  }
  __syncthreads();
  if (t < DH){
    float s_new = (redq[0] + redq[1]) * 0.08838834764831845f + mask[CC];
    float pn = __expf(s_new - M);
    float Lf = Ls[0] + Ls[1] + Ls[2] + Ls[3] + pn;
    float of = osum[0][t] + osum[1][t] + osum[2][t] + osum[3][t]
             + pn * vnew[kv * DH + t];
    attn_in[qh * DH + t] = of / Lf;
  }
}

// ---- K5: o_proj GEMV. One wave per output element, pinned 8-deep batch.
__global__ void k_oproj(const float* __restrict__ attn_in,
                        const float* __restrict__ Wo,
                        float* __restrict__ out){
  int wave = threadIdx.x >> 6, lane = threadIdx.x & 63;
  int e = blockIdx.x * 4 + wave;
  const float* W = Wo + (size_t)e * HID;
  float4 wb[8], xb[8];
  #pragma unroll
  for (int j = 0; j < 8; ++j) wb[j] = *(const float4*)(W + (j * 64 + lane) * 4);
  #pragma unroll
  for (int j = 0; j < 8; ++j) xb[j] = *(const float4*)(attn_in + (j * 64 + lane) * 4);
  __builtin_amdgcn_sched_barrier(0);
  float acc = 0.f;
  #pragma unroll
  for (int j = 0; j < 8; ++j)
    acc += wb[j].x*xb[j].x + wb[j].y*xb[j].y + wb[j].z*xb[j].z + wb[j].w*xb[j].w;
  #pragma unroll
  for (int off = 32; off; off >>= 1) acc += __shfl_down(acc, off, 64);
  if (lane == 0) out[e] = acc;
}

// ---- K6: DIAGNOSTIC clock probe. 40,000 dependent FMAs = 160k cycles.
// dur_us reads the effective shader clock: ~67 us @2.4 GHz, ~229 us @700 MHz.
__global__ void k_spin(const float* __restrict__ x, float* __restrict__ sink){
  float a = x[threadIdx.x];
  for (int i = 0; i < 1000; ++i){
    #pragma unroll
    for (int j = 0; j < 40; ++j) a = __builtin_fmaf(a, 1.0000001f, 1e-9f);
  }
  sink[threadIdx.x] = a;   // scratch write keeps the chain live
}

extern "C" void kernel_launch(void* const* d_in, const int* in_sizes, int n_in,
                              void* d_out, int out_size, void* d_ws, size_t ws_size,
                              hipStream_t stream){
  const float* x    = (const float*)d_in[0];
  const float* cosb = (const float*)d_in[1];
  const float* sinb = (const float*)d_in[2];
  const float* mask = (const float*)d_in[3];
  const float* kc   = (const float*)d_in[4];
  const float* vc   = (const float*)d_in[5];
  const float* Wq   = (const float*)d_in[6];
  const float* Wk   = (const float*)d_in[7];
  const float* Wv   = (const float*)d_in[8];
  const float* Wo   = (const float*)d_in[9];
  const float* qw   = (const float*)d_in[10];
  const float* kw   = (const float*)d_in[11];
  float* out = (float*)d_out;
  float* ws = (float*)d_ws;
  float* raw     = ws;                          // 4096
  float* qf      = ws + 4096;                   // 2048
  float* kf      = ws + 6144;                   // 1024
  float* ps      = ws + 8192;                   // 8*4*2*16384 = 1048576
  float* opart   = ws + 1056768;                // 16*32*128 = 65536
  float2* ML     = (float2*)(ws + 1122304);     // 512 float2 = 1024 floats
  float* attn_in = ws + 1123328;                // 2048
  float* spin    = ws + 1125376;                // 64

  k_qkv     <<<1024, 256, 0, stream>>>(x, Wq, Wk, Wv, raw, out);
  k_normrope<<<24,   128, 0, stream>>>(raw, cosb, sinb, qw, kw, qf, kf, out);
  k_scores  <<<HKV * NDG * 8, 512, 0, stream>>>(qf, kc, ps);
  k_softpv  <<<HKV * NCH, 512, 0, stream>>>(ps, vc, mask, opart, ML);
  k_combine <<<HQ, 512, 0, stream>>>(opart, ML, qf, kf, raw + 3072, mask, attn_in);
  k_oproj   <<<512, 256, 0, stream>>>(attn_in, Wo, out);
  k_spin    <<<1, 64, 0, stream>>>(x, spin);
}

// Round 8
// 230.247 us; speedup vs baseline: 1.3142x; 1.3142x over previous
//
#include <hip/hip_runtime.h>
#include <math.h>
#include <stddef.h>

#define HQ   16
#define HKV  8
#define DH   128
#define HID  2048
#define CC   16384
#define NCH  32             // flash chunks of 512
#define CHUNK 512

// d_out layout (FLOAT32, 4096 elements): [attn 2048][k_new 8*128][v 8*128]
//
// ws layout (floats): raw @0 (4096); opart @4096 (65536); ML @69632 (1024)

// ---- K1: QKV projections. One wave per output element. Writes raw;
// v rows also go straight to d_out.
__global__ void k_qkv(const float* __restrict__ x,
                      const float* __restrict__ Wq,
                      const float* __restrict__ Wk,
                      const float* __restrict__ Wv,
                      float* __restrict__ raw,
                      float* __restrict__ out){
  int wave = threadIdx.x >> 6, lane = threadIdx.x & 63;
  int e = blockIdx.x * 4 + wave;
  const float* W;
  if (e < 2048)      W = Wq + (size_t)e * HID;
  else if (e < 3072) W = Wk + (size_t)(e - 2048) * HID;
  else               W = Wv + (size_t)(e - 3072) * HID;
  float4 wb[8], xb[8];
  #pragma unroll
  for (int j = 0; j < 8; ++j) wb[j] = *(const float4*)(W + (j * 64 + lane) * 4);
  #pragma unroll
  for (int j = 0; j < 8; ++j) xb[j] = *(const float4*)(x + (j * 64 + lane) * 4);
  __builtin_amdgcn_sched_barrier(0);
  float acc = 0.f;
  #pragma unroll
  for (int j = 0; j < 8; ++j)
    acc += wb[j].x*xb[j].x + wb[j].y*xb[j].y + wb[j].z*xb[j].z + wb[j].w*xb[j].w;
  #pragma unroll
  for (int off = 32; off; off >>= 1) acc += __shfl_down(acc, off, 64);
  if (lane == 0){
    raw[e] = acc;
    if (e >= 3072) out[e] = acc;   // v passthrough
  }
}

// ---- K2: flash-decode with fused q-RMSNorm+RoPE. grid = HKV*NCH = 256 x 512.
// Lane l of a wave holds elems l and l+64 of a 128-row, so the RoPE pair
// (i, i+64) is lane-local: one shfl-reduce per row, no LDS staging.
__global__ __launch_bounds__(512) void k_flash(
    const float* __restrict__ raw,     // q rows [0..2047]
    const float* __restrict__ cosb,
    const float* __restrict__ sinb,
    const float* __restrict__ qw,
    const float* __restrict__ kcache,  // [HKV][DH][CC]
    const float* __restrict__ vcache,  // [HKV][CC][DH]
    const float* __restrict__ mask,    // [CC+1]
    float* __restrict__ opart,         // [HQ][NCH][DH]
    float2* __restrict__ ml){          // [HQ][NCH]
  __shared__ float q_s[2][DH];
  __shared__ float sc_part[8][2][CHUNK];   // 32 KB
  __shared__ float p_s[2][CHUNK];          // 4 KB
  __shared__ float part[2][16][DH];        // 16 KB
  __shared__ float red[32];
  int kv = blockIdx.x >> 5, ch = blockIdx.x & 31;
  int c0 = ch << 9;                        // * CHUNK
  int t = threadIdx.x;
  const float scale = 0.08838834764831845f;  // 128^-0.5

  // fused q norm+rope: waves 0,1 each handle one q head
  {
    int w = t >> 6, l = t & 63;
    if (w < 2){
      int qh = kv * 2 + w;
      const float* src = raw + qh * DH;
      float v0 = src[l], v1 = src[l + 64];
      float ss = v0 * v0 + v1 * v1;
      #pragma unroll
      for (int off = 32; off; off >>= 1) ss += __shfl_down(ss, off, 64);
      ss = __shfl(ss, 0, 64);
      float rms = sqrtf(ss * (1.f / 128.f) + 1e-6f);
      float n0 = v0 / rms * qw[l], n1 = v1 / rms * qw[l + 64];
      q_s[w][l]      = n0 * cosb[l]      - n1 * sinb[l];
      q_s[w][l + 64] = n1 * cosb[l + 64] + n0 * sinb[l + 64];
    }
  }
  __syncthreads();

  // ---- Phase A: QK^T. 8 d-groups x 64 lanes; 4 positions x 2 halves each.
  {
    int dg = t >> 6, ln = t & 63;
    const float* kp = kcache + (size_t)kv * DH * CC + (size_t)(dg * 16) * CC + c0 + ln * 4;
    float qr0[16], qr1[16];
    #pragma unroll
    for (int i = 0; i < 16; ++i){
      qr0[i] = q_s[0][dg * 16 + i];
      qr1[i] = q_s[1][dg * 16 + i];
    }
    #pragma unroll
    for (int half = 0; half < 2; ++half){
      const float* kph = kp + half * 256;
      float4 kb[8], kc2[8];
      #pragma unroll
      for (int j = 0; j < 8; ++j) kb[j]  = *(const float4*)(kph + (size_t)j * CC);
      #pragma unroll
      for (int j = 0; j < 8; ++j) kc2[j] = *(const float4*)(kph + (size_t)(j + 8) * CC);
      __builtin_amdgcn_sched_barrier(0);
      float a00 = 0.f, a01 = 0.f, a02 = 0.f, a03 = 0.f;
      float a10 = 0.f, a11 = 0.f, a12 = 0.f, a13 = 0.f;
      #pragma unroll
      for (int j = 0; j < 8; ++j){
        a00 += qr0[j] * kb[j].x;  a01 += qr0[j] * kb[j].y;
        a02 += qr0[j] * kb[j].z;  a03 += qr0[j] * kb[j].w;
        a10 += qr1[j] * kb[j].x;  a11 += qr1[j] * kb[j].y;
        a12 += qr1[j] * kb[j].z;  a13 += qr1[j] * kb[j].w;
      }
      #pragma unroll
      for (int j = 0; j < 8; ++j){
        a00 += qr0[8 + j] * kc2[j].x;  a01 += qr0[8 + j] * kc2[j].y;
        a02 += qr0[8 + j] * kc2[j].z;  a03 += qr0[8 + j] * kc2[j].w;
        a10 += qr1[8 + j] * kc2[j].x;  a11 += qr1[8 + j] * kc2[j].y;
        a12 += qr1[8 + j] * kc2[j].z;  a13 += qr1[8 + j] * kc2[j].w;
      }
      *(float4*)&sc_part[dg][0][half * 256 + ln * 4] = make_float4(a00, a01, a02, a03);
      *(float4*)&sc_part[dg][1][half * 256 + ln * 4] = make_float4(a10, a11, a12, a13);
    }
  }
  __syncthreads();

  // ---- Phase B: combine partials, chunk softmax. Thread t <-> position t.
  int wv = t >> 6;
  float s0, s1;
  {
    float acc0 = 0.f, acc1 = 0.f;
    #pragma unroll
    for (int dg = 0; dg < 8; ++dg){
      acc0 += sc_part[dg][0][t];
      acc1 += sc_part[dg][1][t];
    }
    float mk = mask[c0 + t];
    s0 = acc0 * scale + mk;
    s1 = acc1 * scale + mk;
  }
  float lm0 = s0, lm1 = s1;
  #pragma unroll
  for (int off = 32; off; off >>= 1){
    lm0 = fmaxf(lm0, __shfl_down(lm0, off, 64));
    lm1 = fmaxf(lm1, __shfl_down(lm1, off, 64));
  }
  if ((t & 63) == 0){ red[wv] = lm0; red[8 + wv] = lm1; }
  __syncthreads();
  float m0 = red[0], m1 = red[8];
  #pragma unroll
  for (int i = 1; i < 8; ++i){
    m0 = fmaxf(m0, red[i]);
    m1 = fmaxf(m1, red[8 + i]);
  }
  float p0 = __expf(s0 - m0);
  float p1 = __expf(s1 - m1);
  p_s[0][t] = p0;
  p_s[1][t] = p1;
  float ls0 = p0, ls1 = p1;
  #pragma unroll
  for (int off = 32; off; off >>= 1){
    ls0 += __shfl_down(ls0, off, 64);
    ls1 += __shfl_down(ls1, off, 64);
  }
  if ((t & 63) == 0){ red[16 + wv] = ls0; red[24 + wv] = ls1; }
  __syncthreads();
  if (t == 0){
    float l0 = 0.f, l1 = 0.f;
    #pragma unroll
    for (int i = 0; i < 8; ++i){ l0 += red[16 + i]; l1 += red[24 + i]; }
    ml[(size_t)(kv * 2)     * NCH + ch] = make_float2(m0, l0);
    ml[(size_t)(kv * 2 + 1) * NCH + ch] = make_float2(m1, l1);
  }

  // ---- Phase C: partial O. 16 pos-slices x 32 dim-lanes; pinned 8-deep.
  {
    int sl = t >> 5, d4 = (t & 31) * 4;
    const float* vbase = vcache + (size_t)kv * CC * DH + (size_t)c0 * DH + d4;
    float4 a0 = make_float4(0.f, 0.f, 0.f, 0.f);
    float4 a1 = make_float4(0.f, 0.f, 0.f, 0.f);
    #pragma unroll
    for (int ib = 0; ib < 4; ++ib){
      float4 vv[8];
      #pragma unroll
      for (int j = 0; j < 8; ++j){
        int off = (ib * 8 + j) * 16 + sl;
        vv[j] = *(const float4*)(vbase + (size_t)off * DH);
      }
      __builtin_amdgcn_sched_barrier(0);
      #pragma unroll
      for (int j = 0; j < 8; ++j){
        int off = (ib * 8 + j) * 16 + sl;
        float pp0 = p_s[0][off], pp1 = p_s[1][off];
        a0.x += pp0 * vv[j].x; a0.y += pp0 * vv[j].y; a0.z += pp0 * vv[j].z; a0.w += pp0 * vv[j].w;
        a1.x += pp1 * vv[j].x; a1.y += pp1 * vv[j].y; a1.z += pp1 * vv[j].z; a1.w += pp1 * vv[j].w;
      }
    }
    *(float4*)&part[0][sl][d4] = a0;
    *(float4*)&part[1][sl][d4] = a1;
  }
  __syncthreads();
  if (t < 256){
    int hh = t >> 7, d = t & 127;
    float o = 0.f;
    #pragma unroll
    for (int ss = 0; ss < 16; ++ss) o += part[hh][ss][d];
    int qh = kv * 2 + hh;
    opart[((size_t)qh * NCH + ch) * DH + d] = o;
  }
}

// ---- K3: fused {q/k norm+rope, k_new write, chunk combine, o_proj}.
// grid = 32 blocks x 512 threads. Each block redundantly rebuilds qf/kf
// (cheap: 24 rows) and the combined attn vector (reads opart 256 KB),
// then computes its 64 o_proj outputs.
__global__ __launch_bounds__(512) void k_out(
    const float* __restrict__ raw,     // [q 2048][k 1024][v 1024]
    const float* __restrict__ cosb,
    const float* __restrict__ sinb,
    const float* __restrict__ qw,
    const float* __restrict__ kw,
    const float* __restrict__ opart,   // [HQ][NCH][DH]
    const float2* __restrict__ ml,     // [HQ][NCH]
    const float* __restrict__ mask,    // [CC+1]
    const float* __restrict__ Wo,
    float* __restrict__ out){
  __shared__ float qk_s[24][DH];       // 12 KB: rows 0-15 qf, 16-23 kf
  __shared__ float snew_s[HQ];
  __shared__ float attn_s[HQ * DH];    // 8 KB
  int b = blockIdx.x, t = threadIdx.x;
  int w = t >> 6, l = t & 63;
  const float scale = 0.08838834764831845f;

  // Step 1: norm+rope rows w, w+8, w+16 (16 q + 8 k). Lane-local RoPE pair.
  #pragma unroll
  for (int rep = 0; rep < 3; ++rep){
    int r = w + rep * 8;
    bool isq = (r < 16);
    int h = isq ? r : r - 16;
    const float* src = isq ? raw + h * DH : raw + 2048 + h * DH;
    float v0 = src[l], v1 = src[l + 64];
    float ss = v0 * v0 + v1 * v1;
    #pragma unroll
    for (int off = 32; off; off >>= 1) ss += __shfl_down(ss, off, 64);
    ss = __shfl(ss, 0, 64);
    float rms = sqrtf(ss * (1.f / 128.f) + 1e-6f);
    const float* wt = isq ? qw : kw;
    float n0 = v0 / rms * wt[l], n1 = v1 / rms * wt[l + 64];
    qk_s[r][l]      = n0 * cosb[l]      - n1 * sinb[l];
    qk_s[r][l + 64] = n1 * cosb[l + 64] + n0 * sinb[l + 64];
  }
  __syncthreads();

  // k_new to d_out (block 0 only): out[2048 + h*128 + d]
  if (b == 0){
    #pragma unroll
    for (int rep = 0; rep < 2; ++rep){
      int idx = t + rep * 512;          // 0..1023
      out[2048 + idx] = qk_s[16 + (idx >> 7)][idx & 127];
    }
  }

  // Step 2: s_new per q head. Wave w handles qh = 2w, 2w+1.
  #pragma unroll
  for (int rep = 0; rep < 2; ++rep){
    int qh = w * 2 + rep;
    int kvh = qh >> 1;
    float p = qk_s[qh][l] * qk_s[16 + kvh][l]
            + qk_s[qh][l + 64] * qk_s[16 + kvh][l + 64];
    #pragma unroll
    for (int off = 32; off; off >>= 1) p += __shfl_down(p, off, 64);
    if (l == 0) snew_s[qh] = p * scale + mask[CC];
  }
  __syncthreads();

  // Step 3: combine chunks into attn_s. Thread covers 4 (qh,d) pairs.
  #pragma unroll
  for (int rep = 0; rep < 4; ++rep){
    int idx = t + rep * 512;            // 0..2047
    int qh = idx >> 7, d = idx & 127;
    int kv = qh >> 1;
    const float2* mlrow = ml + (size_t)qh * NCH;
    float M = -1e30f;
    #pragma unroll
    for (int c = 0; c < NCH; ++c) M = fmaxf(M, mlrow[c].x);
    float o = 0.f, L = 0.f;
    #pragma unroll 4
    for (int c = 0; c < NCH; ++c){
      float2 m2 = mlrow[c];
      float wgt = __expf(m2.x - M);
      L += m2.y * wgt;
      o += wgt * opart[((size_t)qh * NCH + c) * DH + d];
    }
    float pn = __expf(snew_s[qh] - M);
    L += pn;
    o += pn * raw[3072 + kv * DH + d];  // vnew
    attn_s[idx] = o / L;
  }
  __syncthreads();

  // Step 4: o_proj. Block b owns outputs e = b*64 .. b*64+63; wave w does 8.
  #pragma unroll
  for (int oo = 0; oo < 8; ++oo){
    int e = b * 64 + w * 8 + oo;
    const float* Wr = Wo + (size_t)e * HID;
    float4 wb[8];
    #pragma unroll
    for (int j = 0; j < 8; ++j) wb[j] = *(const float4*)(Wr + (j * 64 + l) * 4);
    float acc = 0.f;
    #pragma unroll
    for (int j = 0; j < 8; ++j){
      float4 xf = *(const float4*)(attn_s + (j * 64 + l) * 4);
      acc += wb[j].x*xf.x + wb[j].y*xf.y + wb[j].z*xf.z + wb[j].w*xf.w;
    }
    #pragma unroll
    for (int off = 32; off; off >>= 1) acc += __shfl_down(acc, off, 64);
    if (l == 0) out[e] = acc;
  }
}

extern "C" void kernel_launch(void* const* d_in, const int* in_sizes, int n_in,
                              void* d_out, int out_size, void* d_ws, size_t ws_size,
                              hipStream_t stream){
  const float* x    = (const float*)d_in[0];
  const float* cosb = (const float*)d_in[1];
  const float* sinb = (const float*)d_in[2];
  const float* mask = (const float*)d_in[3];
  const float* kc   = (const float*)d_in[4];
  const float* vc   = (const float*)d_in[5];
  const float* Wq   = (const float*)d_in[6];
  const float* Wk   = (const float*)d_in[7];
  const float* Wv   = (const float*)d_in[8];
  const float* Wo   = (const float*)d_in[9];
  const float* qw   = (const float*)d_in[10];
  const float* kw   = (const float*)d_in[11];
  float* out = (float*)d_out;
  float* ws = (float*)d_ws;
  float* raw   = ws;                        // 4096
  float* opart = ws + 4096;                 // 16*32*128 = 65536
  float2* ML   = (float2*)(ws + 69632);     // 512 float2 = 1024 floats

  k_qkv  <<<1024, 256, 0, stream>>>(x, Wq, Wk, Wv, raw, out);
  k_flash<<<HKV * NCH, 512, 0, stream>>>(raw, cosb, sinb, qw, kc, vc, mask,
                                         opart, ML);
  k_out  <<<32, 512, 0, stream>>>(raw, cosb, sinb, qw, kw, opart, ML, mask,
                                  Wo, out);
}

// Round 9
// 226.584 us; speedup vs baseline: 1.3354x; 1.0162x over previous
//
#include <hip/hip_runtime.h>
#include <math.h>
#include <stddef.h>

#define HQ   16
#define HKV  8
#define DH   128
#define HID  2048
#define CC   16384
#define NCH  32             // position chunks of 512 in k_softpv
#define CHUNK 512
#define NDG  4              // dim-groups of 32 in k_scores

// d_out layout (FLOAT32, 4096 elements): [attn 2048][k_new 8*128][v 8*128]
//
// ws layout (floats):
//   raw     @0        (4096)
//   qf      @4096     (2048)
//   kf      @6144     (1024)      (vnew = raw+3072)
//   ps      @8192     (1048576)   partial scores [HKV][NDG][2][CC]
//   opart   @1056768  (65536)     [HQ][NCH][DH]
//   ML      @1122304  (1024)      [HQ][NCH] float2
//   attn_in @1123328  (2048)

// ---- K1: QKV projections. One wave per output element.
__global__ void k_qkv(const float* __restrict__ x,
                      const float* __restrict__ Wq,
                      const float* __restrict__ Wk,
                      const float* __restrict__ Wv,
                      float* __restrict__ raw,
                      float* __restrict__ out){
  int wave = threadIdx.x >> 6, lane = threadIdx.x & 63;
  int e = blockIdx.x * 4 + wave;
  const float* W;
  if (e < 2048)      W = Wq + (size_t)e * HID;
  else if (e < 3072) W = Wk + (size_t)(e - 2048) * HID;
  else               W = Wv + (size_t)(e - 3072) * HID;
  float4 wb[8], xb[8];
  #pragma unroll
  for (int j = 0; j < 8; ++j) wb[j] = *(const float4*)(W + (j * 64 + lane) * 4);
  #pragma unroll
  for (int j = 0; j < 8; ++j) xb[j] = *(const float4*)(x + (j * 64 + lane) * 4);
  __builtin_amdgcn_sched_barrier(0);
  float acc = 0.f;
  #pragma unroll
  for (int j = 0; j < 8; ++j)
    acc += wb[j].x*xb[j].x + wb[j].y*xb[j].y + wb[j].z*xb[j].z + wb[j].w*xb[j].w;
  #pragma unroll
  for (int off = 32; off; off >>= 1) acc += __shfl_down(acc, off, 64);
  if (lane == 0){
    raw[e] = acc;
    if (e >= 3072) out[e] = acc;   // v passthrough
  }
}

// ---- K2: RMSNorm + RoPE (q,k). grid=24, 128 threads.
__global__ void k_normrope(const float* __restrict__ raw,
                           const float* __restrict__ cosb,
                           const float* __restrict__ sinb,
                           const float* __restrict__ qw,
                           const float* __restrict__ kw,
                           float* __restrict__ qf,
                           float* __restrict__ kf,
                           float* __restrict__ out){
  __shared__ float lds[DH];
  __shared__ float wsum[2];
  int b = blockIdx.x, t = threadIdx.x;
  bool isq = (b < 16);
  int h = isq ? b : b - 16;
  float val = isq ? raw[h * DH + t] : raw[2048 + h * DH + t];
  float ss = val * val;
  #pragma unroll
  for (int off = 32; off; off >>= 1) ss += __shfl_down(ss, off, 64);
  if ((t & 63) == 0) wsum[t >> 6] = ss;
  __syncthreads();
  float rms = sqrtf((wsum[0] + wsum[1]) / 128.f + 1e-6f);
  float w = isq ? qw[t] : kw[t];
  float normed = val / rms * w;
  lds[t] = normed;
  __syncthreads();
  float rot = (t < 64) ? -lds[t + 64] : lds[t - 64];
  float res = normed * cosb[t] + rot * sinb[t];
  if (isq) qf[h * DH + t] = res;
  else { kf[h * DH + t] = res; out[2048 + h * DH + t] = res; }
}

// ---- K3a: QK^T partial scores, pure streaming (no barriers in hot loop).
// grid = HKV*NDG*8 = 256 blocks x 512 threads.
__global__ __launch_bounds__(512) void k_scores(
    const float* __restrict__ qf,
    const float* __restrict__ kcache,  // [HKV][DH][CC]
    float* __restrict__ ps){           // [HKV][NDG][2][CC]
  __shared__ float q_s[2][32];
  int kv = blockIdx.x >> 5, dg = (blockIdx.x >> 3) & 3, cs = blockIdx.x & 7;
  int t = threadIdx.x;
  if (t < 64) q_s[t >> 5][t & 31] = qf[(kv * 2 + (t >> 5)) * DH + dg * 32 + (t & 31)];
  __syncthreads();
  const float* kp = kcache + (size_t)kv * DH * CC + (size_t)(dg * 32) * CC
                  + cs * 2048 + t * 4;
  float a00 = 0.f, a01 = 0.f, a02 = 0.f, a03 = 0.f;
  float a10 = 0.f, a11 = 0.f, a12 = 0.f, a13 = 0.f;
  #pragma unroll
  for (int ib = 0; ib < 4; ++ib){
    float4 kb[8];
    #pragma unroll
    for (int j = 0; j < 8; ++j)
      kb[j] = *(const float4*)(kp + (size_t)(ib * 8 + j) * CC);
    __builtin_amdgcn_sched_barrier(0);
    #pragma unroll
    for (int j = 0; j < 8; ++j){
      float q0 = q_s[0][ib * 8 + j], q1 = q_s[1][ib * 8 + j];
      a00 += q0 * kb[j].x; a01 += q0 * kb[j].y; a02 += q0 * kb[j].z; a03 += q0 * kb[j].w;
      a10 += q1 * kb[j].x; a11 += q1 * kb[j].y; a12 += q1 * kb[j].z; a13 += q1 * kb[j].w;
    }
  }
  size_t base = ((size_t)(kv * NDG + dg) * 2) * CC + cs * 2048 + t * 4;
  *(float4*)(ps + base)      = make_float4(a00, a01, a02, a03);
  *(float4*)(ps + base + CC) = make_float4(a10, a11, a12, a13);
}

// ---- K3b: combine partials, softmax per chunk, PV. grid = HKV*NCH = 256 x 512.
__global__ __launch_bounds__(512) void k_softpv(
    const float* __restrict__ ps,      // [HKV][NDG][2][CC]
    const float* __restrict__ vcache,  // [HKV][CC][DH]
    const float* __restrict__ mask,    // [CC+1]
    float* __restrict__ opart,         // [HQ][NCH][DH]
    float2* __restrict__ ml){          // [HQ][NCH]
  __shared__ float p_s[2][CHUNK];      // 4 KB
  __shared__ float part[2][16][DH];    // 16 KB
  __shared__ float red[32];
  int kv = blockIdx.x >> 5, ch = blockIdx.x & 31;
  int c0 = ch << 9;
  int t = threadIdx.x;
  const float scale = 0.08838834764831845f;  // 128^-0.5

  float s0 = 0.f, s1 = 0.f;
  #pragma unroll
  for (int dg = 0; dg < NDG; ++dg){
    size_t base = ((size_t)(kv * NDG + dg) * 2) * CC + c0 + t;
    s0 += ps[base];
    s1 += ps[base + CC];
  }
  {
    float mk = mask[c0 + t];
    s0 = s0 * scale + mk;
    s1 = s1 * scale + mk;
  }
  int wv = t >> 6;
  float lm0 = s0, lm1 = s1;
  #pragma unroll
  for (int off = 32; off; off >>= 1){
    lm0 = fmaxf(lm0, __shfl_down(lm0, off, 64));
    lm1 = fmaxf(lm1, __shfl_down(lm1, off, 64));
  }
  if ((t & 63) == 0){ red[wv] = lm0; red[8 + wv] = lm1; }
  __syncthreads();
  float m0 = red[0], m1 = red[8];
  #pragma unroll
  for (int i = 1; i < 8; ++i){
    m0 = fmaxf(m0, red[i]);
    m1 = fmaxf(m1, red[8 + i]);
  }
  float p0 = __expf(s0 - m0);
  float p1 = __expf(s1 - m1);
  p_s[0][t] = p0;
  p_s[1][t] = p1;
  float ls0 = p0, ls1 = p1;
  #pragma unroll
  for (int off = 32; off; off >>= 1){
    ls0 += __shfl_down(ls0, off, 64);
    ls1 += __shfl_down(ls1, off, 64);
  }
  if ((t & 63) == 0){ red[16 + wv] = ls0; red[24 + wv] = ls1; }
  __syncthreads();
  if (t == 0){
    float l0 = 0.f, l1 = 0.f;
    #pragma unroll
    for (int i = 0; i < 8; ++i){ l0 += red[16 + i]; l1 += red[24 + i]; }
    ml[(size_t)(kv * 2)     * NCH + ch] = make_float2(m0, l0);
    ml[(size_t)(kv * 2 + 1) * NCH + ch] = make_float2(m1, l1);
  }

  {
    int sl = t >> 5, d4 = (t & 31) * 4;
    const float* vbase = vcache + (size_t)kv * CC * DH + (size_t)c0 * DH + d4;
    float4 a0 = make_float4(0.f, 0.f, 0.f, 0.f);
    float4 a1 = make_float4(0.f, 0.f, 0.f, 0.f);
    #pragma unroll
    for (int ib = 0; ib < 4; ++ib){
      float4 vv[8];
      #pragma unroll
      for (int j = 0; j < 8; ++j){
        int off = (ib * 8 + j) * 16 + sl;
        vv[j] = *(const float4*)(vbase + (size_t)off * DH);
      }
      __builtin_amdgcn_sched_barrier(0);
      #pragma unroll
      for (int j = 0; j < 8; ++j){
        int off = (ib * 8 + j) * 16 + sl;
        float pp0 = p_s[0][off], pp1 = p_s[1][off];
        a0.x += pp0 * vv[j].x; a0.y += pp0 * vv[j].y; a0.z += pp0 * vv[j].z; a0.w += pp0 * vv[j].w;
        a1.x += pp1 * vv[j].x; a1.y += pp1 * vv[j].y; a1.z += pp1 * vv[j].z; a1.w += pp1 * vv[j].w;
      }
    }
    *(float4*)&part[0][sl][d4] = a0;
    *(float4*)&part[1][sl][d4] = a1;
  }
  __syncthreads();
  if (t < 256){
    int hh = t >> 7, d = t & 127;
    float o = 0.f;
    #pragma unroll
    for (int ss = 0; ss < 16; ++ss) o += part[hh][ss][d];
    int qh = kv * 2 + hh;
    opart[((size_t)qh * NCH + ch) * DH + d] = o;
  }
}

// ---- K4: combine chunk partials + new-token term. grid=HQ, 512 threads.
__global__ void k_combine(const float* __restrict__ opart,
                          const float2* __restrict__ ml,
                          const float* __restrict__ qf,
                          const float* __restrict__ kf,
                          const float* __restrict__ vnew,   // raw+3072: [HKV][DH]
                          const float* __restrict__ mask,
                          float* __restrict__ attn_in){
  __shared__ float osum[4][DH];
  __shared__ float Ls[4];
  __shared__ float redm[8];
  __shared__ float redq[2];
  int qh = blockIdx.x, t = threadIdx.x;
  int g = t >> 7, d = t & 127;
  int kv = qh >> 1;
  const float2* mlrow = ml + (size_t)qh * NCH;
  float mm = mlrow[t & 31].x;
  #pragma unroll
  for (int off = 32; off; off >>= 1) mm = fmaxf(mm, __shfl_down(mm, off, 64));
  if ((t & 63) == 0) redm[t >> 6] = mm;
  __syncthreads();
  float M = fmaxf(redm[0], redm[1]);
  float o = 0.f, L = 0.f;
  int ch0 = g * 8;
  #pragma unroll
  for (int i = 0; i < 8; ++i){
    float2 m2 = mlrow[ch0 + i];
    float w = __expf(m2.x - M);
    L += m2.y * w;
    o += w * opart[((size_t)qh * NCH + ch0 + i) * DH + d];
  }
  osum[g][d] = o;
  if (d == 0) Ls[g] = L;
  if (t < DH){
    float sum = qf[qh * DH + t] * kf[kv * DH + t];
    #pragma unroll
    for (int off = 32; off; off >>= 1) sum += __shfl_down(sum, off, 64);
    if ((t & 63) == 0) redq[t >> 6] = sum;
  }
  __syncthreads();
  if (t < DH){
    float s_new = (redq[0] + redq[1]) * 0.08838834764831845f + mask[CC];
    float pn = __expf(s_new - M);
    float Lf = Ls[0] + Ls[1] + Ls[2] + Ls[3] + pn;
    float of = osum[0][t] + osum[1][t] + osum[2][t] + osum[3][t]
             + pn * vnew[kv * DH + t];
    attn_in[qh * DH + t] = of / Lf;
  }
}

// ---- K5: o_proj GEMV. One wave per output element, pinned 8-deep batch.
__global__ void k_oproj(const float* __restrict__ attn_in,
                        const float* __restrict__ Wo,
                        float* __restrict__ out){
  int wave = threadIdx.x >> 6, lane = threadIdx.x & 63;
  int e = blockIdx.x * 4 + wave;
  const float* W = Wo + (size_t)e * HID;
  float4 wb[8], xb[8];
  #pragma unroll
  for (int j = 0; j < 8; ++j) wb[j] = *(const float4*)(W + (j * 64 + lane) * 4);
  #pragma unroll
  for (int j = 0; j < 8; ++j) xb[j] = *(const float4*)(attn_in + (j * 64 + lane) * 4);
  __builtin_amdgcn_sched_barrier(0);
  float acc = 0.f;
  #pragma unroll
  for (int j = 0; j < 8; ++j)
    acc += wb[j].x*xb[j].x + wb[j].y*xb[j].y + wb[j].z*xb[j].z + wb[j].w*xb[j].w;
  #pragma unroll
  for (int off = 32; off; off >>= 1) acc += __shfl_down(acc, off, 64);
  if (lane == 0) out[e] = acc;
}

extern "C" void kernel_launch(void* const* d_in, const int* in_sizes, int n_in,
                              void* d_out, int out_size, void* d_ws, size_t ws_size,
                              hipStream_t stream){
  const float* x    = (const float*)d_in[0];
  const float* cosb = (const float*)d_in[1];
  const float* sinb = (const float*)d_in[2];
  const float* mask = (const float*)d_in[3];
  const float* kc   = (const float*)d_in[4];
  const float* vc   = (const float*)d_in[5];
  const float* Wq   = (const float*)d_in[6];
  const float* Wk   = (const float*)d_in[7];
  const float* Wv   = (const float*)d_in[8];
  const float* Wo   = (const float*)d_in[9];
  const float* qw   = (const float*)d_in[10];
  const float* kw   = (const float*)d_in[11];
  float* out = (float*)d_out;
  float* ws = (float*)d_ws;
  float* raw     = ws;                          // 4096
  float* qf      = ws + 4096;                   // 2048
  float* kf      = ws + 6144;                   // 1024
  float* ps      = ws + 8192;                   // 8*4*2*16384 = 1048576
  float* opart   = ws + 1056768;                // 16*32*128 = 65536
  float2* ML     = (float2*)(ws + 1122304);     // 512 float2 = 1024 floats
  float* attn_in = ws + 1123328;                // 2048

  k_qkv     <<<1024, 256, 0, stream>>>(x, Wq, Wk, Wv, raw, out);
  k_normrope<<<24,   128, 0, stream>>>(raw, cosb, sinb, qw, kw, qf, kf, out);
  k_scores  <<<HKV * NDG * 8, 512, 0, stream>>>(qf, kc, ps);
  k_softpv  <<<HKV * NCH, 512, 0, stream>>>(ps, vc, mask, opart, ML);
  k_combine <<<HQ, 512, 0, stream>>>(opart, ML, qf, kf, raw + 3072, mask, attn_in);
  k_oproj   <<<512, 256, 0, stream>>>(attn_in, Wo, out);
}

// Round 10
// 216.783 us; speedup vs baseline: 1.3958x; 1.0452x over previous
//
#include <hip/hip_runtime.h>
#include <math.h>
#include <stddef.h>

#define HQ   16
#define HKV  8
#define DH   128
#define HID  2048
#define CC   16384
#define NCH  64             // position chunks of 256 in k_softpv
#define CHUNK 256
#define NDG  8              // dim-groups of 16 in k_scores

// d_out layout (FLOAT32, 4096 elements): [attn 2048][k_new 8*128][v 8*128]
//
// ws layout (floats):
//   raw     @0        (4096)
//   qf      @4096     (2048)
//   kf      @6144     (1024)      (vnew = raw+3072)
//   ps      @8192     (2097152)   partial scores [HKV][NDG][2][CC] = 8 MB
//   opart   @2105344  (131072)    [HQ][NCH][DH]
//   ML      @2236416  (2048)      [HQ][NCH] float2
//   attn_in @2238464  (2048)

// ---- K1: QKV projections. One wave per output element.
__global__ void k_qkv(const float* __restrict__ x,
                      const float* __restrict__ Wq,
                      const float* __restrict__ Wk,
                      const float* __restrict__ Wv,
                      float* __restrict__ raw,
                      float* __restrict__ out){
  int wave = threadIdx.x >> 6, lane = threadIdx.x & 63;
  int e = blockIdx.x * 4 + wave;
  const float* W;
  if (e < 2048)      W = Wq + (size_t)e * HID;
  else if (e < 3072) W = Wk + (size_t)(e - 2048) * HID;
  else               W = Wv + (size_t)(e - 3072) * HID;
  float4 wb[8], xb[8];
  #pragma unroll
  for (int j = 0; j < 8; ++j) wb[j] = *(const float4*)(W + (j * 64 + lane) * 4);
  #pragma unroll
  for (int j = 0; j < 8; ++j) xb[j] = *(const float4*)(x + (j * 64 + lane) * 4);
  __builtin_amdgcn_sched_barrier(0);
  float acc = 0.f;
  #pragma unroll
  for (int j = 0; j < 8; ++j)
    acc += wb[j].x*xb[j].x + wb[j].y*xb[j].y + wb[j].z*xb[j].z + wb[j].w*xb[j].w;
  #pragma unroll
  for (int off = 32; off; off >>= 1) acc += __shfl_down(acc, off, 64);
  if (lane == 0){
    raw[e] = acc;
    if (e >= 3072) out[e] = acc;   // v passthrough
  }
}

// ---- K2: RMSNorm + RoPE (q,k). grid=24, 128 threads.
__global__ void k_normrope(const float* __restrict__ raw,
                           const float* __restrict__ cosb,
                           const float* __restrict__ sinb,
                           const float* __restrict__ qw,
                           const float* __restrict__ kw,
                           float* __restrict__ qf,
                           float* __restrict__ kf,
                           float* __restrict__ out){
  __shared__ float lds[DH];
  __shared__ float wsum[2];
  int b = blockIdx.x, t = threadIdx.x;
  bool isq = (b < 16);
  int h = isq ? b : b - 16;
  float val = isq ? raw[h * DH + t] : raw[2048 + h * DH + t];
  float ss = val * val;
  #pragma unroll
  for (int off = 32; off; off >>= 1) ss += __shfl_down(ss, off, 64);
  if ((t & 63) == 0) wsum[t >> 6] = ss;
  __syncthreads();
  float rms = sqrtf((wsum[0] + wsum[1]) / 128.f + 1e-6f);
  float w = isq ? qw[t] : kw[t];
  float normed = val / rms * w;
  lds[t] = normed;
  __syncthreads();
  float rot = (t < 64) ? -lds[t + 64] : lds[t - 64];
  float res = normed * cosb[t] + rot * sinb[t];
  if (isq) qf[h * DH + t] = res;
  else { kf[h * DH + t] = res; out[2048 + h * DH + t] = res; }
}

// ---- K3a: QK^T partial scores, max-concurrency streaming.
// grid = HKV*NDG*32 = 2048 blocks x 128 threads (16 waves/CU, no hot barriers).
// Block (kv, dg, cs): dims dg*16..+15, positions cs*512..+511.
__global__ __launch_bounds__(128) void k_scores(
    const float* __restrict__ qf,
    const float* __restrict__ kcache,  // [HKV][DH][CC]
    float* __restrict__ ps){           // [HKV][NDG][2][CC]
  __shared__ float q_s[2][16];
  int kv = blockIdx.x >> 8, dg = (blockIdx.x >> 5) & 7, cs = blockIdx.x & 31;
  int t = threadIdx.x;
  if (t < 32) q_s[t >> 4][t & 15] = qf[(kv * 2 + (t >> 4)) * DH + dg * 16 + (t & 15)];
  __syncthreads();
  const float* kp = kcache + (size_t)kv * DH * CC + (size_t)(dg * 16) * CC
                  + cs * 512 + t * 4;
  float a00 = 0.f, a01 = 0.f, a02 = 0.f, a03 = 0.f;
  float a10 = 0.f, a11 = 0.f, a12 = 0.f, a13 = 0.f;
  #pragma unroll
  for (int ib = 0; ib < 2; ++ib){
    float4 kb[8];
    #pragma unroll
    for (int j = 0; j < 8; ++j)
      kb[j] = *(const float4*)(kp + (size_t)(ib * 8 + j) * CC);
    __builtin_amdgcn_sched_barrier(0);
    #pragma unroll
    for (int j = 0; j < 8; ++j){
      float q0 = q_s[0][ib * 8 + j], q1 = q_s[1][ib * 8 + j];
      a00 += q0 * kb[j].x; a01 += q0 * kb[j].y; a02 += q0 * kb[j].z; a03 += q0 * kb[j].w;
      a10 += q1 * kb[j].x; a11 += q1 * kb[j].y; a12 += q1 * kb[j].z; a13 += q1 * kb[j].w;
    }
  }
  size_t base = ((size_t)(kv * NDG + dg) * 2) * CC + cs * 512 + t * 4;
  *(float4*)(ps + base)      = make_float4(a00, a01, a02, a03);
  *(float4*)(ps + base + CC) = make_float4(a10, a11, a12, a13);
}

// ---- K3b: combine partials, softmax per 256-chunk, PV.
// grid = HKV*NCH = 512 blocks x 256 threads (2 blocks/CU, phase-decoupled).
__global__ __launch_bounds__(256) void k_softpv(
    const float* __restrict__ ps,      // [HKV][NDG][2][CC]
    const float* __restrict__ vcache,  // [HKV][CC][DH]
    const float* __restrict__ mask,    // [CC+1]
    float* __restrict__ opart,         // [HQ][NCH][DH]
    float2* __restrict__ ml){          // [HQ][NCH]
  __shared__ float p_s[2][CHUNK];      // 2 KB
  __shared__ float part[2][8][DH];     // 8 KB
  __shared__ float red[16];
  int kv = blockIdx.x >> 6, ch = blockIdx.x & 63;
  int c0 = ch << 8;
  int t = threadIdx.x;
  const float scale = 0.08838834764831845f;  // 128^-0.5

  // gather partial dots for position c0+t, both heads
  float s0 = 0.f, s1 = 0.f;
  #pragma unroll
  for (int dg = 0; dg < NDG; ++dg){
    size_t base = ((size_t)(kv * NDG + dg) * 2) * CC + c0 + t;
    s0 += ps[base];
    s1 += ps[base + CC];
  }
  {
    float mk = mask[c0 + t];
    s0 = s0 * scale + mk;
    s1 = s1 * scale + mk;
  }
  // chunk softmax over 256 positions (4 waves)
  int wv = t >> 6;
  float lm0 = s0, lm1 = s1;
  #pragma unroll
  for (int off = 32; off; off >>= 1){
    lm0 = fmaxf(lm0, __shfl_down(lm0, off, 64));
    lm1 = fmaxf(lm1, __shfl_down(lm1, off, 64));
  }
  if ((t & 63) == 0){ red[wv] = lm0; red[4 + wv] = lm1; }
  __syncthreads();
  float m0 = fmaxf(fmaxf(red[0], red[1]), fmaxf(red[2], red[3]));
  float m1 = fmaxf(fmaxf(red[4], red[5]), fmaxf(red[6], red[7]));
  float p0 = __expf(s0 - m0);
  float p1 = __expf(s1 - m1);
  p_s[0][t] = p0;
  p_s[1][t] = p1;
  float ls0 = p0, ls1 = p1;
  #pragma unroll
  for (int off = 32; off; off >>= 1){
    ls0 += __shfl_down(ls0, off, 64);
    ls1 += __shfl_down(ls1, off, 64);
  }
  if ((t & 63) == 0){ red[8 + wv] = ls0; red[12 + wv] = ls1; }
  __syncthreads();
  if (t == 0){
    float l0 = red[8] + red[9] + red[10] + red[11];
    float l1 = red[12] + red[13] + red[14] + red[15];
    ml[(size_t)(kv * 2)     * NCH + ch] = make_float2(m0, l0);
    ml[(size_t)(kv * 2 + 1) * NCH + ch] = make_float2(m1, l1);
  }

  // PV: 8 pos-slices x 32 dim-lanes; pinned 8-deep batches; V contiguous.
  {
    int sl = t >> 5, d4 = (t & 31) * 4;
    const float* vbase = vcache + (size_t)kv * CC * DH + (size_t)c0 * DH + d4;
    float4 a0 = make_float4(0.f, 0.f, 0.f, 0.f);
    float4 a1 = make_float4(0.f, 0.f, 0.f, 0.f);
    #pragma unroll
    for (int ib = 0; ib < 4; ++ib){
      float4 vv[8];
      #pragma unroll
      for (int j = 0; j < 8; ++j){
        int off = (ib * 8 + j) * 8 + sl;
        vv[j] = *(const float4*)(vbase + (size_t)off * DH);
      }
      __builtin_amdgcn_sched_barrier(0);
      #pragma unroll
      for (int j = 0; j < 8; ++j){
        int off = (ib * 8 + j) * 8 + sl;
        float pp0 = p_s[0][off], pp1 = p_s[1][off];
        a0.x += pp0 * vv[j].x; a0.y += pp0 * vv[j].y; a0.z += pp0 * vv[j].z; a0.w += pp0 * vv[j].w;
        a1.x += pp1 * vv[j].x; a1.y += pp1 * vv[j].y; a1.z += pp1 * vv[j].z; a1.w += pp1 * vv[j].w;
      }
    }
    *(float4*)&part[0][sl][d4] = a0;
    *(float4*)&part[1][sl][d4] = a1;
  }
  __syncthreads();
  {
    int hh = t >> 7, d = t & 127;
    float o = 0.f;
    #pragma unroll
    for (int ss = 0; ss < 8; ++ss) o += part[hh][ss][d];
    int qh = kv * 2 + hh;
    opart[((size_t)qh * NCH + ch) * DH + d] = o;
  }
}

// ---- K4: combine chunk partials + new-token term. grid=HQ, 512 threads.
// 4 groups x 16 chunks each (NCH=64).
__global__ void k_combine(const float* __restrict__ opart,
                          const float2* __restrict__ ml,
                          const float* __restrict__ qf,
                          const float* __restrict__ kf,
                          const float* __restrict__ vnew,   // raw+3072: [HKV][DH]
                          const float* __restrict__ mask,
                          float* __restrict__ attn_in){
  __shared__ float osum[4][DH];
  __shared__ float Ls[4];
  __shared__ float redm[8];
  __shared__ float redq[2];
  int qh = blockIdx.x, t = threadIdx.x;
  int g = t >> 7, d = t & 127;
  int kv = qh >> 1;
  const float2* mlrow = ml + (size_t)qh * NCH;
  float mm = mlrow[t & 63].x;     // each wave's 64 lanes cover all 64 chunks
  #pragma unroll
  for (int off = 32; off; off >>= 1) mm = fmaxf(mm, __shfl_down(mm, off, 64));
  if ((t & 63) == 0) redm[t >> 6] = mm;
  __syncthreads();
  float M = fmaxf(redm[0], redm[1]);
  float o = 0.f, L = 0.f;
  int ch0 = g * 16;
  #pragma unroll
  for (int i = 0; i < 16; ++i){
    float2 m2 = mlrow[ch0 + i];
    float w = __expf(m2.x - M);
    L += m2.y * w;
    o += w * opart[((size_t)qh * NCH + ch0 + i) * DH + d];
  }
  osum[g][d] = o;
  if (d == 0) Ls[g] = L;
  if (t < DH){
    float sum = qf[qh * DH + t] * kf[kv * DH + t];
    #pragma unroll
    for (int off = 32; off; off >>= 1) sum += __shfl_down(sum, off, 64);
    if ((t & 63) == 0) redq[t >> 6] = sum;
  }
  __syncthreads();
  if (t < DH){
    float s_new = (redq[0] + redq[1]) * 0.08838834764831845f + mask[CC];
    float pn = __expf(s_new - M);
    float Lf = Ls[0] + Ls[1] + Ls[2] + Ls[3] + pn;
    float of = osum[0][t] + osum[1][t] + osum[2][t] + osum[3][t]
             + pn * vnew[kv * DH + t];
    attn_in[qh * DH + t] = of / Lf;
  }
}

// ---- K5: o_proj GEMV. One wave per output element, pinned 8-deep batch.
__global__ void k_oproj(const float* __restrict__ attn_in,
                        const float* __restrict__ Wo,
                        float* __restrict__ out){
  int wave = threadIdx.x >> 6, lane = threadIdx.x & 63;
  int e = blockIdx.x * 4 + wave;
  const float* W = Wo + (size_t)e * HID;
  float4 wb[8], xb[8];
  #pragma unroll
  for (int j = 0; j < 8; ++j) wb[j] = *(const float4*)(W + (j * 64 + lane) * 4);
  #pragma unroll
  for (int j = 0; j < 8; ++j) xb[j] = *(const float4*)(attn_in + (j * 64 + lane) * 4);
  __builtin_amdgcn_sched_barrier(0);
  float acc = 0.f;
  #pragma unroll
  for (int j = 0; j < 8; ++j)
    acc += wb[j].x*xb[j].x + wb[j].y*xb[j].y + wb[j].z*xb[j].z + wb[j].w*xb[j].w;
  #pragma unroll
  for (int off = 32; off; off >>= 1) acc += __shfl_down(acc, off, 64);
  if (lane == 0) out[e] = acc;
}

extern "C" void kernel_launch(void* const* d_in, const int* in_sizes, int n_in,
                              void* d_out, int out_size, void* d_ws, size_t ws_size,
                              hipStream_t stream){
  const float* x    = (const float*)d_in[0];
  const float* cosb = (const float*)d_in[1];
  const float* sinb = (const float*)d_in[2];
  const float* mask = (const float*)d_in[3];
  const float* kc   = (const float*)d_in[4];
  const float* vc   = (const float*)d_in[5];
  const float* Wq   = (const float*)d_in[6];
  const float* Wk   = (const float*)d_in[7];
  const float* Wv   = (const float*)d_in[8];
  const float* Wo   = (const float*)d_in[9];
  const float* qw   = (const float*)d_in[10];
  const float* kw   = (const float*)d_in[11];
  float* out = (float*)d_out;
  float* ws = (float*)d_ws;
  float* raw     = ws;                          // 4096
  float* qf      = ws + 4096;                   // 2048
  float* kf      = ws + 6144;                   // 1024
  float* ps      = ws + 8192;                   // 8*8*2*16384 = 2097152
  float* opart   = ws + 2105344;                // 16*64*128 = 131072
  float2* ML     = (float2*)(ws + 2236416);     // 1024 float2 = 2048 floats
  float* attn_in = ws + 2238464;                // 2048

  k_qkv     <<<1024, 256, 0, stream>>>(x, Wq, Wk, Wv, raw, out);
  k_normrope<<<24,   128, 0, stream>>>(raw, cosb, sinb, qw, kw, qf, kf, out);
  k_scores  <<<HKV * NDG * 32, 128, 0, stream>>>(qf, kc, ps);
  k_softpv  <<<HKV * NCH, 256, 0, stream>>>(ps, vc, mask, opart, ML);
  k_combine <<<HQ, 512, 0, stream>>>(opart, ML, qf, kf, raw + 3072, mask, attn_in);
  k_oproj   <<<512, 256, 0, stream>>>(attn_in, Wo, out);
}